// Round 1
// baseline (1324.896 us; speedup 1.0000x reference)
//
#include <hip/hip_runtime.h>
#include <hip/hip_bf16.h>

#define AS1 __attribute__((address_space(1)))
#define AS3 __attribute__((address_space(3)))

typedef __bf16 bf16_t;
typedef __attribute__((ext_vector_type(8))) __bf16 bfrag;
typedef __attribute__((ext_vector_type(4))) __bf16 bf16x4;
typedef __attribute__((ext_vector_type(2))) __bf16 bf16x2;
typedef __attribute__((ext_vector_type(4))) float ffrag;

#define S_LEN 2048
#define B_DIM 16
#define H_DIM 1024
#define N3H   3072
#define M_DIM 32768  /* S*B */
#define CHUNK 64
#define NCHUNK 32    /* S_LEN / CHUNK */
#define BH    16384  /* B*H */

__device__ __forceinline__ float sigmoidf_(float x) {
  return 1.0f / (1.0f + __expf(-x));
}
__device__ __forceinline__ float tanh_fast(float x) {
  return 2.0f / (1.0f + __expf(-2.0f * x)) - 1.0f;
}

// ---------------- embedding gather: X[s*B+b][h] = bf16(emb[x[s*B+b]][h]) ---
__global__ __launch_bounds__(256) void embed_kernel(
    const int* __restrict__ x, const float* __restrict__ emb,
    bf16_t* __restrict__ X)
{
  const int row = blockIdx.x;            // 0..32767 = s*16+b
  const int v = x[row];
  const float4* src = (const float4*)(emb + (size_t)v * H_DIM);
  float4 f = src[threadIdx.x];
  bf16x4 o;
  o.x = (__bf16)f.x; o.y = (__bf16)f.y; o.z = (__bf16)f.z; o.w = (__bf16)f.w;
  ((bf16x4*)X)[(size_t)row * (H_DIM / 4) + threadIdx.x] = o;
}

// ---------------- weight fp32 -> bf16 --------------------------------------
__global__ __launch_bounds__(256) void cvtw_kernel(
    const float* __restrict__ W, bf16_t* __restrict__ Wb)
{
  const size_t i = (size_t)blockIdx.x * 256 + threadIdx.x;  // float4 index
  float4 f = ((const float4*)W)[i];
  bf16x4 o;
  o.x = (__bf16)f.x; o.y = (__bf16)f.y; o.z = (__bf16)f.z; o.w = (__bf16)f.w;
  ((bf16x4*)Wb)[i] = o;
}

// ---------------- GEMM  Y = act(X * W^T + b) -------------------------------
// 256x256 tile, BK=64 split as two 32-k halves; 8 waves (2M x 4N), each wave
// owns 128x64 of C (acc[8][4]). LDS = 128 KiB: {A,B} x {buf0,buf1} x {k0,k1},
// each slot 256 rows x 32 k x 2B = 16 KiB, chunk-XOR swizzled (involution:
// pre-swizzled global source for global_load_lds, swizzled ds_read offset).
// 8-phase schedule per iteration (2 K-tiles). Each phase:
//   ds_read frags | stage one freed half-tile (2x global_load_lds) |
//   s_barrier | lgkmcnt(0) | setprio(1) 16xMFMA setprio(0) | [vmcnt(4) @P4/P8] | s_barrier
// Counted vmcnt: 4 newest loads (2 half-tiles) stay in flight across barriers.
// Slot lifetimes audited: every slot has >=1 full barrier between its last
// ds_read (all waves) and its re-staging, and a vmcnt wait + barrier between
// its staging and its first ds_read.
__global__ __launch_bounds__(512, 2) void gemm_act_kernel(
    const bf16_t* __restrict__ A,
    const bf16_t* __restrict__ Bw,
    const float* __restrict__ bias,
    bf16_t* __restrict__ Y)
{
  constexpr int K = H_DIM;   // 1024 -> 16 K-tiles of 64 -> 8 iterations
  constexpr int N = N3H;     // 3072
  extern __shared__ char lds[] __attribute__((aligned(16)));
  // byte layout: Aslot(b,ks) = b*32768 + ks*16384 ; Bslot = 65536 + same

  const int tid  = threadIdx.x;
  const int lane = tid & 63;
  const int wave = tid >> 6;
  const int wr = wave >> 2;      // 0..1  M
  const int wc = wave & 3;       // 0..3  N
  const int fr = lane & 15;
  const int quad = lane >> 4;

  // XCD-aware swizzle: 1536 blocks = 8 XCDs x 192 (bijective, 1536%8==0)
  const int bid = blockIdx.x;
  const int swz = (bid & 7) * 192 + (bid >> 3);
  const long m0 = (long)(swz / 12) * 256;
  const long n0 = (long)(swz % 12) * 256;

  // staging: thread -> (row = c*128 + tid>>2, chunk = tid&3); source chunk
  // pre-swizzled by (row>>1)&3 so linear LDS + swizzled read = involution.
  const int sr = tid >> 2;
  const int sc = ((tid & 3) ^ ((tid >> 3) & 3)) * 8;
  const bf16_t* Asrc = A  + (m0 + sr) * K + sc;
  const bf16_t* Bsrc = Bw + (n0 + sr) * K + sc;
  char* AwrB = lds + wave * 1024;                 // wave-uniform dest bases
  char* BwrB = lds + 65536 + wave * 1024;

  // fragment reads: row = (wr*128|wc*64) + idx*16 + fr, chunk = quad^((fr>>1)&3)
  const int roff = fr * 64 + ((quad ^ ((fr >> 1) & 3)) * 16);
  const char* Ard = lds + wr * 8192 + roff;
  const char* Brd = lds + 65536 + wc * 4096 + roff;

  ffrag acc[8][4] = {};
  bfrag af[8], bfv[2];

#define STAGE_A(buf, ks, kofs) do {                                            \
    const bf16_t* _s = Asrc + (kofs) + (ks) * 32;                              \
    char* _d = AwrB + (buf) * 32768 + (ks) * 16384;                            \
    __builtin_amdgcn_global_load_lds((AS1 void*)_s, (AS3 void*)_d, 16, 0, 0);  \
    __builtin_amdgcn_global_load_lds((AS1 void*)(_s + 128 * K),                \
                                     (AS3 void*)(_d + 8192), 16, 0, 0);        \
  } while (0)
#define STAGE_B(buf, ks, kofs) do {                                            \
    const bf16_t* _s = Bsrc + (kofs) + (ks) * 32;                              \
    char* _d = BwrB + (buf) * 32768 + (ks) * 16384;                            \
    __builtin_amdgcn_global_load_lds((AS1 void*)_s, (AS3 void*)_d, 16, 0, 0);  \
    __builtin_amdgcn_global_load_lds((AS1 void*)(_s + 128 * K),                \
                                     (AS3 void*)(_d + 8192), 16, 0, 0);        \
  } while (0)
#define LOAD_AF(buf, ks) do {                                                  \
    _Pragma("unroll")                                                          \
    for (int mi = 0; mi < 8; ++mi)                                             \
      af[mi] = *(const bfrag*)(Ard + (buf) * 32768 + (ks) * 16384 + mi * 1024);\
  } while (0)
#define LOAD_BF(buf, ks, nh) do {                                              \
    bfv[0] = *(const bfrag*)(Brd + (buf) * 32768 + (ks) * 16384 + (2*(nh)) * 1024);     \
    bfv[1] = *(const bfrag*)(Brd + (buf) * 32768 + (ks) * 16384 + (2*(nh)+1) * 1024);   \
  } while (0)
#define MFMA_NH(nh) do {                                                       \
    __builtin_amdgcn_s_setprio(1);                                             \
    _Pragma("unroll")                                                          \
    for (int mi = 0; mi < 8; ++mi) {                                           \
      acc[mi][2*(nh)]   = __builtin_amdgcn_mfma_f32_16x16x32_bf16(af[mi], bfv[0], acc[mi][2*(nh)],   0, 0, 0); \
      acc[mi][2*(nh)+1] = __builtin_amdgcn_mfma_f32_16x16x32_bf16(af[mi], bfv[1], acc[mi][2*(nh)+1], 0, 0, 0); \
    }                                                                          \
    __builtin_amdgcn_s_setprio(0);                                             \
  } while (0)
#define BARX() do {                                                            \
    __builtin_amdgcn_sched_barrier(0);                                         \
    __builtin_amdgcn_s_barrier();                                              \
    __builtin_amdgcn_sched_barrier(0);                                         \
  } while (0)
#define WAIT_LGKM0() do { asm volatile("s_waitcnt lgkmcnt(0)" ::: "memory");   \
    __builtin_amdgcn_sched_barrier(0); } while (0)
#define WAIT_VM4()   asm volatile("s_waitcnt vmcnt(4)" ::: "memory")
#define WAIT_VM0()   asm volatile("s_waitcnt vmcnt(0)" ::: "memory")

  // prologue: T0 both halves -> buf0 (oldest 8 loads), T1.k0 -> buf1 (4 newest)
  STAGE_A(0, 0, 0);   STAGE_B(0, 0, 0);
  STAGE_A(0, 1, 0);   STAGE_B(0, 1, 0);
  STAGE_A(1, 0, 64);  STAGE_B(1, 0, 64);
  WAIT_VM4();          // buf0 complete, buf1.k0 in flight
  BARX();

  for (int t = 0; t < 8; ++t) {
    const int kof1 = (2 * t + 1) * 64;   // T1 = 2t+1 (always valid, <=15)
    const int kof2 = (2 * t + 2) * 64;   // T2
    const int kof3 = (2 * t + 3) * 64;   // T3
    const bool st = (t < 7);             // stage T2/T3?

    // P1: buf0.k0 x n01 | stage buf1.A.k1 <- T1
    LOAD_AF(0, 0); LOAD_BF(0, 0, 0);
    STAGE_A(1, 1, kof1);
    BARX(); WAIT_LGKM0();
    MFMA_NH(0);
    BARX();

    // P2: buf0.k0 x n23 | stage buf1.B.k1 <- T1
    LOAD_BF(0, 0, 1);
    STAGE_B(1, 1, kof1);
    BARX(); WAIT_LGKM0();
    MFMA_NH(1);
    BARX();

    // P3: buf0.k1 x n01 | stage buf0.A.k0 <- T2 (slot freed after P1)
    LOAD_AF(0, 1); LOAD_BF(0, 1, 0);
    if (st) STAGE_A(0, 0, kof2);
    BARX(); WAIT_LGKM0();
    MFMA_NH(0);
    BARX();

    // P4: buf0.k1 x n23 | stage buf0.B.k0 <- T2 | counted wait
    LOAD_BF(0, 1, 1);
    if (st) STAGE_B(0, 0, kof2);
    BARX(); WAIT_LGKM0();
    MFMA_NH(1);
    if (st) WAIT_VM4(); else WAIT_VM0();   // ensure loads through P2 landed
    BARX();

    // P5: buf1.k0 x n01 | stage buf0.A.k1 <- T2
    LOAD_AF(1, 0); LOAD_BF(1, 0, 0);
    if (st) STAGE_A(0, 1, kof2);
    BARX(); WAIT_LGKM0();
    MFMA_NH(0);
    BARX();

    // P6: buf1.k0 x n23 | stage buf0.B.k1 <- T2
    LOAD_BF(1, 0, 1);
    if (st) STAGE_B(0, 1, kof2);
    BARX(); WAIT_LGKM0();
    MFMA_NH(1);
    BARX();

    // P7: buf1.k1 x n01 | stage buf1.A.k0 <- T3
    LOAD_AF(1, 1); LOAD_BF(1, 1, 0);
    if (st) STAGE_A(1, 0, kof3);
    BARX(); WAIT_LGKM0();
    MFMA_NH(0);
    BARX();

    // P8: buf1.k1 x n23 | stage buf1.B.k0 <- T3 | counted wait
    LOAD_BF(1, 1, 1);
    if (st) STAGE_B(1, 0, kof3);
    BARX(); WAIT_LGKM0();
    MFMA_NH(1);
    if (st) WAIT_VM4();                    // ensure loads through P6 landed
    BARX();
  }

  // epilogue: D row m = wr*128 + mi*16 + quad*4 + reg, col n = wc*64 + nj*16 + fr
#pragma unroll
  for (int nj = 0; nj < 4; ++nj) {
    const long n = n0 + wc * 64 + nj * 16 + fr;
    const float bv = bias[n];
    const bool is_tanh = (n < H_DIM);
#pragma unroll
    for (int mi = 0; mi < 8; ++mi) {
#pragma unroll
      for (int reg = 0; reg < 4; ++reg) {
        const long m = m0 + wr * 128 + mi * 16 + quad * 4 + reg;
        float y = acc[mi][nj][reg] + bv;
        float a = is_tanh ? tanh_fast(y) : sigmoidf_(y);
        Y[m * N + n] = (bf16_t)a;
      }
    }
  }
#undef STAGE_A
#undef STAGE_B
#undef LOAD_AF
#undef LOAD_BF
#undef MFMA_NH
#undef BARX
#undef WAIT_LGKM0
#undef WAIT_VM4
#undef WAIT_VM0
}

// ---------------- chunked parallel scan (bf16 Y, 2-wide vectorized) --------
__global__ __launch_bounds__(256) void scan_pass1(
    const bf16_t* __restrict__ Y, float* __restrict__ Ag, float* __restrict__ Dg)
{
  const int idx = blockIdx.x * 256 + threadIdx.x;   // g*8192 + b*512 + h2
  const int g = idx >> 13;
  const int b = (idx >> 9) & 15;
  const int h2 = idx & 511;
  const bf16_t* p = Y + ((size_t)(g * CHUNK * B_DIM + b)) * N3H + h2 * 2;
  float A0 = 1.0f, A1 = 1.0f, c0 = 0.0f, c1 = 0.0f;
  for (int i = 0; i < CHUNK; ++i) {
    const bf16x2 zv = *(const bf16x2*)(p);
    const bf16x2 fv = *(const bf16x2*)(p + H_DIM);
    const float f0 = (float)fv[0], f1 = (float)fv[1];
    const float a0 = 1.0f - f0,    a1 = 1.0f - f1;
    c0 = f0 * (float)zv[0] + a0 * c0;
    c1 = f1 * (float)zv[1] + a1 * c1;
    A0 *= a0;
    A1 *= a1;
    p += (size_t)B_DIM * N3H;
  }
  const int base = g * BH + b * H_DIM + h2 * 2;
  *(float2*)(Ag + base) = make_float2(A0, A1);
  *(float2*)(Dg + base) = make_float2(c0, c1);
}

__global__ __launch_bounds__(256) void scan_pass2(
    const float* __restrict__ Ag, const float* __restrict__ Dg,
    float* __restrict__ Cs)
{
  const int j = blockIdx.x * 256 + threadIdx.x;     // 0..16383
  float c = 0.0f;
#pragma unroll
  for (int g = 0; g < NCHUNK; ++g) {
    Cs[g * BH + j] = c;
    c = Dg[g * BH + j] + Ag[g * BH + j] * c;
  }
}

__global__ __launch_bounds__(256) void scan_pass3(
    const bf16_t* __restrict__ Y, const float* __restrict__ Cs,
    bf16_t* __restrict__ Xn, float* __restrict__ Out, const int last)
{
  const int idx = blockIdx.x * 256 + threadIdx.x;   // g*8192 + b*512 + h2
  const int g = idx >> 13;
  const int b = (idx >> 9) & 15;
  const int h2 = idx & 511;
  const bf16_t* p = Y + ((size_t)(g * CHUNK * B_DIM + b)) * N3H + h2 * 2;
  const int cb = g * BH + b * H_DIM + h2 * 2;
  float c0 = Cs[cb], c1 = Cs[cb + 1];
  size_t oo = (size_t)g * CHUNK * BH + (size_t)b * H_DIM + h2 * 2;
  for (int i = 0; i < CHUNK; ++i) {
    const bf16x2 zv = *(const bf16x2*)(p);
    const bf16x2 fv = *(const bf16x2*)(p + H_DIM);
    const bf16x2 ov = *(const bf16x2*)(p + 2 * H_DIM);
    const float f0 = (float)fv[0], f1 = (float)fv[1];
    c0 = f0 * (float)zv[0] + (1.0f - f0) * c0;
    c1 = f1 * (float)zv[1] + (1.0f - f1) * c1;
    const float v0 = (float)ov[0] * c0;
    const float v1 = (float)ov[1] * c1;
    if (last) {
      const int s = g * CHUNK + i;
      if (s < S_LEN - 1) *(float2*)(Out + oo) = make_float2(v0, v1);  // out = X[:-1]
    } else {
      bf16x2 w; w[0] = (__bf16)v0; w[1] = (__bf16)v1;
      *(bf16x2*)(Xn + oo) = w;
    }
    p += (size_t)B_DIM * N3H;
    oo += (size_t)BH;
  }
}

extern "C" void kernel_launch(void* const* d_in, const int* in_sizes, int n_in,
                              void* d_out, int out_size, void* d_ws, size_t ws_size,
                              hipStream_t stream)
{
  const int*   x   = (const int*)d_in[0];
  const float* emb = (const float*)d_in[1];
  const float* W[3]  = {(const float*)d_in[2], (const float*)d_in[4], (const float*)d_in[6]};
  const float* bv[3] = {(const float*)d_in[3], (const float*)d_in[5], (const float*)d_in[7]};
  float* out = (float*)d_out;

  char* ws = (char*)d_ws;
  bf16_t* Xbf = (bf16_t*)ws;                                // 67,108,864 B
  bf16_t* Wbf = (bf16_t*)(ws + 67108864);                   //  6,291,456 B
  bf16_t* Yb  = (bf16_t*)(ws + 67108864 + 6291456);         // 201,326,592 B
  char* tail  = ws + 67108864 + 6291456 + 201326592;
  float* Ag = (float*)tail;                                 // 2,097,152 B
  float* Dg = (float*)(tail + 2097152);                     // 2,097,152 B
  float* Cs = (float*)(tail + 4194304);                     // 2,097,152 B
  (void)ws_size;

  // 128 KiB dynamic LDS needs the opt-in attribute (HK pattern); host-side,
  // not stream-associated -> graph-capture safe.
  hipFuncSetAttribute((const void*)gemm_act_kernel,
                      hipFuncAttributeMaxDynamicSharedMemorySize, 131072);

  embed_kernel<<<M_DIM, 256, 0, stream>>>(x, emb, Xbf);

  for (int l = 0; l < 3; ++l) {
    const int last = (l == 2);
    cvtw_kernel<<<3072, 256, 0, stream>>>(W[l], Wbf);
    gemm_act_kernel<<<1536, 512, 131072, stream>>>(Xbf, Wbf, bv[l], Yb);
    scan_pass1<<<1024, 256, 0, stream>>>(Yb, Ag, Dg);
    scan_pass2<<<64, 256, 0, stream>>>(Ag, Dg, Cs);
    scan_pass3<<<1024, 256, 0, stream>>>(Yb, Cs, Xbf, out, last);
  }
}

// Round 2
// 1301.599 us; speedup vs baseline: 1.0179x; 1.0179x over previous
//
#include <hip/hip_runtime.h>
#include <hip/hip_bf16.h>

#define AS1 __attribute__((address_space(1)))
#define AS3 __attribute__((address_space(3)))

typedef __bf16 bf16_t;
typedef __attribute__((ext_vector_type(8))) __bf16 bfrag;
typedef __attribute__((ext_vector_type(4))) __bf16 bf16x4;
typedef __attribute__((ext_vector_type(2))) __bf16 bf16x2;
typedef __attribute__((ext_vector_type(4))) float ffrag;

#define S_LEN 2048
#define B_DIM 16
#define H_DIM 1024
#define N3H   3072
#define M_DIM 32768  /* S*B */
#define CHUNK 64
#define NCHUNK 32    /* S_LEN / CHUNK */
#define BH    16384  /* B*H */

__device__ __forceinline__ float sigmoidf_(float x) {
  return 1.0f / (1.0f + __expf(-x));
}
__device__ __forceinline__ float tanh_fast(float x) {
  return 2.0f / (1.0f + __expf(-2.0f * x)) - 1.0f;
}

// ---------------- embedding gather: X[s*B+b][h] = bf16(emb[x[s*B+b]][h]) ---
__global__ __launch_bounds__(256) void embed_kernel(
    const int* __restrict__ x, const float* __restrict__ emb,
    bf16_t* __restrict__ X)
{
  const int row = blockIdx.x;            // 0..32767 = s*16+b
  const int v = x[row];
  const float4* src = (const float4*)(emb + (size_t)v * H_DIM);
  float4 f = src[threadIdx.x];
  bf16x4 o;
  o.x = (__bf16)f.x; o.y = (__bf16)f.y; o.z = (__bf16)f.z; o.w = (__bf16)f.w;
  ((bf16x4*)X)[(size_t)row * (H_DIM / 4) + threadIdx.x] = o;
}

// ---------------- weight fp32 -> bf16 --------------------------------------
__global__ __launch_bounds__(256) void cvtw_kernel(
    const float* __restrict__ W, bf16_t* __restrict__ Wb)
{
  const size_t i = (size_t)blockIdx.x * 256 + threadIdx.x;  // float4 index
  float4 f = ((const float4*)W)[i];
  bf16x4 o;
  o.x = (__bf16)f.x; o.y = (__bf16)f.y; o.z = (__bf16)f.z; o.w = (__bf16)f.w;
  ((bf16x4*)Wb)[i] = o;
}

// ---------------- GEMM  Y = act(X * W^T + b) -------------------------------
// 256x256 tile, BK=64 split as two 32-k halves; 8 waves (2M x 4N), each wave
// owns 128x64 of C (acc[8][4]). LDS = 128 KiB: {A,B} x {buf0,buf1} x {k0,k1},
// each slot 256 rows x 32 k x 2B = 16 KiB, chunk-XOR swizzled (involution:
// pre-swizzled global source for global_load_lds, swizzled ds_read offset).
// 8-phase schedule per iteration (2 K-tiles); counted vmcnt(4) only at P4/P8.
//
// Epilogue (R1 fix): previous scalar-store epilogue produced 32B segments ->
// WRITE_SIZE 412 MB (2.1x amplification) and ~230 of 306 us. Now: after the
// K-loop's final barrier the 128 KiB LDS is dead and the 256x256 bf16 C-tile
// is exactly 128 KiB -> act->LDS (quad-XOR swizzled, conflict-free), barrier,
// then 16 passes of ds_read_b128 -> coalesced 16B global stores.
__global__ __launch_bounds__(512, 2) void gemm_act_kernel(
    const bf16_t* __restrict__ A,
    const bf16_t* __restrict__ Bw,
    const float* __restrict__ bias,
    bf16_t* __restrict__ Y)
{
  constexpr int K = H_DIM;   // 1024 -> 16 K-tiles of 64 -> 8 iterations
  constexpr int N = N3H;     // 3072
  extern __shared__ char lds[] __attribute__((aligned(16)));
  // byte layout: Aslot(b,ks) = b*32768 + ks*16384 ; Bslot = 65536 + same

  const int tid  = threadIdx.x;
  const int lane = tid & 63;
  const int wave = tid >> 6;
  const int wr = wave >> 2;      // 0..1  M
  const int wc = wave & 3;       // 0..3  N
  const int fr = lane & 15;
  const int quad = lane >> 4;

  // XCD-aware swizzle: 1536 blocks = 8 XCDs x 192 (bijective, 1536%8==0)
  const int bid = blockIdx.x;
  const int swz = (bid & 7) * 192 + (bid >> 3);
  const long m0 = (long)(swz / 12) * 256;
  const long n0 = (long)(swz % 12) * 256;

  // staging: thread -> (row = c*128 + tid>>2, chunk = tid&3); source chunk
  // pre-swizzled by (row>>1)&3 so linear LDS + swizzled read = involution.
  const int sr = tid >> 2;
  const int sc = ((tid & 3) ^ ((tid >> 3) & 3)) * 8;
  const bf16_t* Asrc = A  + (m0 + sr) * K + sc;
  const bf16_t* Bsrc = Bw + (n0 + sr) * K + sc;
  char* AwrB = lds + wave * 1024;                 // wave-uniform dest bases
  char* BwrB = lds + 65536 + wave * 1024;

  // fragment reads: row = (wr*128|wc*64) + idx*16 + fr, chunk = quad^((fr>>1)&3)
  const int roff = fr * 64 + ((quad ^ ((fr >> 1) & 3)) * 16);
  const char* Ard = lds + wr * 8192 + roff;
  const char* Brd = lds + 65536 + wc * 4096 + roff;

  ffrag acc[8][4] = {};
  bfrag af[8], bfv[2];

#define STAGE_A(buf, ks, kofs) do {                                            \
    const bf16_t* _s = Asrc + (kofs) + (ks) * 32;                              \
    char* _d = AwrB + (buf) * 32768 + (ks) * 16384;                            \
    __builtin_amdgcn_global_load_lds((AS1 void*)_s, (AS3 void*)_d, 16, 0, 0);  \
    __builtin_amdgcn_global_load_lds((AS1 void*)(_s + 128 * K),                \
                                     (AS3 void*)(_d + 8192), 16, 0, 0);        \
  } while (0)
#define STAGE_B(buf, ks, kofs) do {                                            \
    const bf16_t* _s = Bsrc + (kofs) + (ks) * 32;                              \
    char* _d = BwrB + (buf) * 32768 + (ks) * 16384;                            \
    __builtin_amdgcn_global_load_lds((AS1 void*)_s, (AS3 void*)_d, 16, 0, 0);  \
    __builtin_amdgcn_global_load_lds((AS1 void*)(_s + 128 * K),                \
                                     (AS3 void*)(_d + 8192), 16, 0, 0);        \
  } while (0)
#define LOAD_AF(buf, ks) do {                                                  \
    _Pragma("unroll")                                                          \
    for (int mi = 0; mi < 8; ++mi)                                             \
      af[mi] = *(const bfrag*)(Ard + (buf) * 32768 + (ks) * 16384 + mi * 1024);\
  } while (0)
#define LOAD_BF(buf, ks, nh) do {                                              \
    bfv[0] = *(const bfrag*)(Brd + (buf) * 32768 + (ks) * 16384 + (2*(nh)) * 1024);     \
    bfv[1] = *(const bfrag*)(Brd + (buf) * 32768 + (ks) * 16384 + (2*(nh)+1) * 1024);   \
  } while (0)
#define MFMA_NH(nh) do {                                                       \
    __builtin_amdgcn_s_setprio(1);                                             \
    _Pragma("unroll")                                                          \
    for (int mi = 0; mi < 8; ++mi) {                                           \
      acc[mi][2*(nh)]   = __builtin_amdgcn_mfma_f32_16x16x32_bf16(af[mi], bfv[0], acc[mi][2*(nh)],   0, 0, 0); \
      acc[mi][2*(nh)+1] = __builtin_amdgcn_mfma_f32_16x16x32_bf16(af[mi], bfv[1], acc[mi][2*(nh)+1], 0, 0, 0); \
    }                                                                          \
    __builtin_amdgcn_s_setprio(0);                                             \
  } while (0)
#define BARX() do {                                                            \
    __builtin_amdgcn_sched_barrier(0);                                         \
    __builtin_amdgcn_s_barrier();                                              \
    __builtin_amdgcn_sched_barrier(0);                                         \
  } while (0)
#define WAIT_LGKM0() do { asm volatile("s_waitcnt lgkmcnt(0)" ::: "memory");   \
    __builtin_amdgcn_sched_barrier(0); } while (0)
#define WAIT_VM4()   asm volatile("s_waitcnt vmcnt(4)" ::: "memory")
#define WAIT_VM0()   asm volatile("s_waitcnt vmcnt(0)" ::: "memory")

  // prologue: T0 both halves -> buf0 (oldest 8 loads), T1.k0 -> buf1 (4 newest)
  STAGE_A(0, 0, 0);   STAGE_B(0, 0, 0);
  STAGE_A(0, 1, 0);   STAGE_B(0, 1, 0);
  STAGE_A(1, 0, 64);  STAGE_B(1, 0, 64);
  WAIT_VM4();          // buf0 complete, buf1.k0 in flight
  BARX();

  for (int t = 0; t < 8; ++t) {
    const int kof1 = (2 * t + 1) * 64;   // T1 = 2t+1 (always valid, <=15)
    const int kof2 = (2 * t + 2) * 64;   // T2
    const int kof3 = (2 * t + 3) * 64;   // T3
    const bool st = (t < 7);             // stage T2/T3?

    // P1: buf0.k0 x n01 | stage buf1.A.k1 <- T1
    LOAD_AF(0, 0); LOAD_BF(0, 0, 0);
    STAGE_A(1, 1, kof1);
    BARX(); WAIT_LGKM0();
    MFMA_NH(0);
    BARX();

    // P2: buf0.k0 x n23 | stage buf1.B.k1 <- T1
    LOAD_BF(0, 0, 1);
    STAGE_B(1, 1, kof1);
    BARX(); WAIT_LGKM0();
    MFMA_NH(1);
    BARX();

    // P3: buf0.k1 x n01 | stage buf0.A.k0 <- T2 (slot freed after P1)
    LOAD_AF(0, 1); LOAD_BF(0, 1, 0);
    if (st) STAGE_A(0, 0, kof2);
    BARX(); WAIT_LGKM0();
    MFMA_NH(0);
    BARX();

    // P4: buf0.k1 x n23 | stage buf0.B.k0 <- T2 | counted wait
    LOAD_BF(0, 1, 1);
    if (st) STAGE_B(0, 0, kof2);
    BARX(); WAIT_LGKM0();
    MFMA_NH(1);
    if (st) WAIT_VM4(); else WAIT_VM0();   // ensure loads through P2 landed
    BARX();

    // P5: buf1.k0 x n01 | stage buf0.A.k1 <- T2
    LOAD_AF(1, 0); LOAD_BF(1, 0, 0);
    if (st) STAGE_A(0, 1, kof2);
    BARX(); WAIT_LGKM0();
    MFMA_NH(0);
    BARX();

    // P6: buf1.k0 x n23 | stage buf0.B.k1 <- T2
    LOAD_BF(1, 0, 1);
    if (st) STAGE_B(0, 1, kof2);
    BARX(); WAIT_LGKM0();
    MFMA_NH(1);
    BARX();

    // P7: buf1.k1 x n01 | stage buf1.A.k0 <- T3
    LOAD_AF(1, 1); LOAD_BF(1, 1, 0);
    if (st) STAGE_A(1, 0, kof3);
    BARX(); WAIT_LGKM0();
    MFMA_NH(0);
    BARX();

    // P8: buf1.k1 x n23 | stage buf1.B.k0 <- T3 | counted wait
    LOAD_BF(1, 1, 1);
    if (st) STAGE_B(1, 0, kof3);
    BARX(); WAIT_LGKM0();
    MFMA_NH(1);
    if (st) WAIT_VM4();                    // ensure loads through P6 landed
    BARX();
  }

  // ---- epilogue: act -> LDS (256 rows x 512 B, quad-XOR swizzled) ----
  // write:  addr = (row*512 + col*2) ^ (quad<<5)   [(row>>2)&3 == quad]
  // lanes of one ds_write_b16: bank = ((nj^quad)<<3) | (fr>>1) -> all 32
  // banks, 2 lanes/bank (free).
  {
    const int xorv = quad << 5;
#pragma unroll
    for (int nj = 0; nj < 4; ++nj) {
      const long n = n0 + wc * 64 + nj * 16 + fr;
      const float bv = bias[n];
      const bool is_tanh = (n < H_DIM);
      const int colb = (wc * 64 + nj * 16 + fr) * 2;
#pragma unroll
      for (int mi = 0; mi < 8; ++mi) {
        const int row0 = wr * 128 + mi * 16 + quad * 4;
#pragma unroll
        for (int reg = 0; reg < 4; ++reg) {
          const float y = acc[mi][nj][reg] + bv;
          const float a = is_tanh ? tanh_fast(y) : sigmoidf_(y);
          *(bf16_t*)(lds + ((((row0 + reg) * 512) + colb) ^ xorv)) = (bf16_t)a;
        }
      }
    }
    __syncthreads();
    // copy out: 16 passes x (512 thr x 16B) = 128 KiB; 32 consecutive lanes
    // cover one contiguous 512B row segment -> fully coalesced 16B stores.
#pragma unroll
    for (int p = 0; p < 16; ++p) {
      const int o = p * 8192 + tid * 16;
      const int rr = o >> 9;           // local row
      const int cb = o & 511;          // byte within row
      const float4 v = *(const float4*)(lds + (((rr * 512) + cb) ^ (((rr >> 2) & 3) << 5)));
      *(float4*)((char*)(Y + (size_t)(m0 + rr) * N + n0) + cb) = v;
    }
  }
#undef STAGE_A
#undef STAGE_B
#undef LOAD_AF
#undef LOAD_BF
#undef MFMA_NH
#undef BARX
#undef WAIT_LGKM0
#undef WAIT_VM4
#undef WAIT_VM0
}

// ---------------- chunked parallel scan (bf16 Y, 2-wide vectorized) --------
__global__ __launch_bounds__(256) void scan_pass1(
    const bf16_t* __restrict__ Y, float* __restrict__ Ag, float* __restrict__ Dg)
{
  const int idx = blockIdx.x * 256 + threadIdx.x;   // g*8192 + b*512 + h2
  const int g = idx >> 13;
  const int b = (idx >> 9) & 15;
  const int h2 = idx & 511;
  const bf16_t* p = Y + ((size_t)(g * CHUNK * B_DIM + b)) * N3H + h2 * 2;
  float A0 = 1.0f, A1 = 1.0f, c0 = 0.0f, c1 = 0.0f;
  for (int i = 0; i < CHUNK; ++i) {
    const bf16x2 zv = *(const bf16x2*)(p);
    const bf16x2 fv = *(const bf16x2*)(p + H_DIM);
    const float f0 = (float)fv[0], f1 = (float)fv[1];
    const float a0 = 1.0f - f0,    a1 = 1.0f - f1;
    c0 = f0 * (float)zv[0] + a0 * c0;
    c1 = f1 * (float)zv[1] + a1 * c1;
    A0 *= a0;
    A1 *= a1;
    p += (size_t)B_DIM * N3H;
  }
  const int base = g * BH + b * H_DIM + h2 * 2;
  *(float2*)(Ag + base) = make_float2(A0, A1);
  *(float2*)(Dg + base) = make_float2(c0, c1);
}

__global__ __launch_bounds__(256) void scan_pass2(
    const float* __restrict__ Ag, const float* __restrict__ Dg,
    float* __restrict__ Cs)
{
  const int j = blockIdx.x * 256 + threadIdx.x;     // 0..16383
  float c = 0.0f;
#pragma unroll
  for (int g = 0; g < NCHUNK; ++g) {
    Cs[g * BH + j] = c;
    c = Dg[g * BH + j] + Ag[g * BH + j] * c;
  }
}

__global__ __launch_bounds__(256) void scan_pass3(
    const bf16_t* __restrict__ Y, const float* __restrict__ Cs,
    bf16_t* __restrict__ Xn, float* __restrict__ Out, const int last)
{
  const int idx = blockIdx.x * 256 + threadIdx.x;   // g*8192 + b*512 + h2
  const int g = idx >> 13;
  const int b = (idx >> 9) & 15;
  const int h2 = idx & 511;
  const bf16_t* p = Y + ((size_t)(g * CHUNK * B_DIM + b)) * N3H + h2 * 2;
  const int cb = g * BH + b * H_DIM + h2 * 2;
  float c0 = Cs[cb], c1 = Cs[cb + 1];
  size_t oo = (size_t)g * CHUNK * BH + (size_t)b * H_DIM + h2 * 2;
  for (int i = 0; i < CHUNK; ++i) {
    const bf16x2 zv = *(const bf16x2*)(p);
    const bf16x2 fv = *(const bf16x2*)(p + H_DIM);
    const bf16x2 ov = *(const bf16x2*)(p + 2 * H_DIM);
    const float f0 = (float)fv[0], f1 = (float)fv[1];
    c0 = f0 * (float)zv[0] + (1.0f - f0) * c0;
    c1 = f1 * (float)zv[1] + (1.0f - f1) * c1;
    const float v0 = (float)ov[0] * c0;
    const float v1 = (float)ov[1] * c1;
    if (last) {
      const int s = g * CHUNK + i;
      if (s < S_LEN - 1) *(float2*)(Out + oo) = make_float2(v0, v1);  // out = X[:-1]
    } else {
      bf16x2 w; w[0] = (__bf16)v0; w[1] = (__bf16)v1;
      *(bf16x2*)(Xn + oo) = w;
    }
    p += (size_t)B_DIM * N3H;
    oo += (size_t)BH;
  }
}

extern "C" void kernel_launch(void* const* d_in, const int* in_sizes, int n_in,
                              void* d_out, int out_size, void* d_ws, size_t ws_size,
                              hipStream_t stream)
{
  const int*   x   = (const int*)d_in[0];
  const float* emb = (const float*)d_in[1];
  const float* W[3]  = {(const float*)d_in[2], (const float*)d_in[4], (const float*)d_in[6]};
  const float* bv[3] = {(const float*)d_in[3], (const float*)d_in[5], (const float*)d_in[7]};
  float* out = (float*)d_out;

  char* ws = (char*)d_ws;
  bf16_t* Xbf = (bf16_t*)ws;                                // 67,108,864 B
  bf16_t* Wbf = (bf16_t*)(ws + 67108864);                   //  6,291,456 B
  bf16_t* Yb  = (bf16_t*)(ws + 67108864 + 6291456);         // 201,326,592 B
  char* tail  = ws + 67108864 + 6291456 + 201326592;
  float* Ag = (float*)tail;                                 // 2,097,152 B
  float* Dg = (float*)(tail + 2097152);                     // 2,097,152 B
  float* Cs = (float*)(tail + 4194304);                     // 2,097,152 B
  (void)ws_size;

  // 128 KiB dynamic LDS needs the opt-in attribute; host-side API, not
  // stream-associated -> graph-capture safe.
  hipFuncSetAttribute((const void*)gemm_act_kernel,
                      hipFuncAttributeMaxDynamicSharedMemorySize, 131072);

  embed_kernel<<<M_DIM, 256, 0, stream>>>(x, emb, Xbf);

  for (int l = 0; l < 3; ++l) {
    const int last = (l == 2);
    cvtw_kernel<<<3072, 256, 0, stream>>>(W[l], Wbf);
    gemm_act_kernel<<<1536, 512, 131072, stream>>>(Xbf, Wbf, bv[l], Yb);
    scan_pass1<<<1024, 256, 0, stream>>>(Yb, Ag, Dg);
    scan_pass2<<<64, 256, 0, stream>>>(Ag, Dg, Cs);
    scan_pass3<<<1024, 256, 0, stream>>>(Yb, Cs, Xbf, out, last);
  }
}

// Round 3
// 1301.257 us; speedup vs baseline: 1.0182x; 1.0003x over previous
//
#include <hip/hip_runtime.h>
#include <hip/hip_bf16.h>

#define AS1 __attribute__((address_space(1)))
#define AS3 __attribute__((address_space(3)))

typedef __bf16 bf16_t;
typedef __attribute__((ext_vector_type(8))) __bf16 bfrag;
typedef __attribute__((ext_vector_type(4))) __bf16 bf16x4;
typedef __attribute__((ext_vector_type(2))) __bf16 bf16x2;
typedef __attribute__((ext_vector_type(4))) float ffrag;

#define S_LEN 2048
#define B_DIM 16
#define H_DIM 1024
#define N3H   3072
#define M_DIM 32768  /* S*B */
#define CHUNK 64
#define NCHUNK 32    /* S_LEN / CHUNK */
#define BH    16384  /* B*H */

__device__ __forceinline__ float sigmoidf_(float x) {
  return 1.0f / (1.0f + __expf(-x));
}
__device__ __forceinline__ float tanh_fast(float x) {
  return 2.0f / (1.0f + __expf(-2.0f * x)) - 1.0f;
}

// ---------------- embedding gather: X[s*B+b][h] = bf16(emb[x[s*B+b]][h]) ---
__global__ __launch_bounds__(256) void embed_kernel(
    const int* __restrict__ x, const float* __restrict__ emb,
    bf16_t* __restrict__ X)
{
  const int row = blockIdx.x;            // 0..32767 = s*16+b
  const int v = x[row];
  const float4* src = (const float4*)(emb + (size_t)v * H_DIM);
  float4 f = src[threadIdx.x];
  bf16x4 o;
  o.x = (__bf16)f.x; o.y = (__bf16)f.y; o.z = (__bf16)f.z; o.w = (__bf16)f.w;
  ((bf16x4*)X)[(size_t)row * (H_DIM / 4) + threadIdx.x] = o;
}

// ---------------- weight fp32 -> bf16 --------------------------------------
__global__ __launch_bounds__(256) void cvtw_kernel(
    const float* __restrict__ W, bf16_t* __restrict__ Wb)
{
  const size_t i = (size_t)blockIdx.x * 256 + threadIdx.x;  // float4 index
  float4 f = ((const float4*)W)[i];
  bf16x4 o;
  o.x = (__bf16)f.x; o.y = (__bf16)f.y; o.z = (__bf16)f.z; o.w = (__bf16)f.w;
  ((bf16x4*)Wb)[i] = o;
}

// ---------------- GEMM  Y = act(X * W^T + b) -------------------------------
// R2 redesign: 256x128 tile, 4 waves (2M x 2N, wave-tile 128x64, acc[8][4]).
// K-tiles of 32, 3-buffer LDS rotation (buf = t%3), stage 2 tiles ahead,
// counted s_waitcnt vmcnt(6) per phase (never 0 until tail), ONE barrier per
// phase. LDS = 3 x (A 16K + B 8K) = 72 KiB -> 2 independent blocks/CU: one
// block's barrier/fill/epilogue stalls overlap the other's MFMA clusters
// (m114 mechanism) while counted-vmcnt pipelines loads within each block.
// Chunk-XOR swizzle identical to the verified R1 kernel (involution:
// pre-swizzled global source for global_load_lds, swizzled ds_read chunk).
// Slot lifetime audit: phase t reads slot t%3 (staged t-2, landed by end-of-
// (t-1) vmcnt(6)+barrier); stages slot (t+2)%3 (last read phase t-1, all
// waves' reads complete before end-of-(t-1) barrier). sched_barrier(0) pins
// ds_read/stage motion across s_barrier and vmcnt.
__global__ __launch_bounds__(256, 2) void gemm_act_kernel(
    const bf16_t* __restrict__ A,
    const bf16_t* __restrict__ Bw,
    const float* __restrict__ bias,
    bf16_t* __restrict__ Y)
{
  constexpr int K = H_DIM;   // 1024 -> 32 K-tiles of 32
  constexpr int N = N3H;     // 3072
  extern __shared__ char lds[] __attribute__((aligned(16)));
  // buf b: A at b*24576 (16384 B = 256 rows x 32k), B at b*24576+16384 (8192 B)

  const int tid  = threadIdx.x;
  const int lane = tid & 63;
  const int wave = tid >> 6;     // 0..3
  const int wr = wave >> 1;      // 0..1  M half (128 rows)
  const int wc = wave & 1;       // 0..1  N half (64 cols)
  const int fr = lane & 15;
  const int quad = lane >> 4;

  // XCD-aware swizzle: 3072 blocks = 8 XCDs x 384 (bijective)
  const int bid = blockIdx.x;
  const int swz = (bid & 7) * 384 + (bid >> 3);
  const long m0 = (long)(swz / 24) * 256;
  const long n0 = (long)(swz % 24) * 128;

  // staging: thread -> (row = tid>>2 within 64-row group, pos = tid&3);
  // source chunk pre-swizzled by ((row>>1)&3) (== (tid>>3)&3).
  const int r  = tid >> 2;
  const int sc = ((tid & 3) ^ ((tid >> 3) & 3)) * 8;
  const bf16_t* As0 = A  + (m0 + r) * K + sc;
  const bf16_t* Bs0 = Bw + (n0 + r) * K + sc;
  const int wdst = wave * 1024;  // wave-uniform LDS dest offset per instr

  // fragment reads: A row = wr*128 + mi*16 + fr, B row = wc*64 + nj*16 + fr,
  // chunk pos = quad ^ ((fr>>1)&3)  (retrieves global k-octet = quad)
  const int cswz = (quad ^ ((fr >> 1) & 3)) * 16;
  const int roffA = wr * 8192 + fr * 64 + cswz;
  const int roffB = wc * 4096 + fr * 64 + cswz;

  ffrag acc[8][4] = {};
  bfrag af[8], bfr[4];

#define STAGE(sb, ke) do {                                                     \
    _Pragma("unroll")                                                          \
    for (int i = 0; i < 4; ++i)                                                \
      __builtin_amdgcn_global_load_lds(                                        \
          (AS1 void*)(As0 + (size_t)i * 64 * K + (ke)),                        \
          (AS3 void*)(lds + (sb) * 24576 + i * 4096 + wdst), 16, 0, 0);        \
    _Pragma("unroll")                                                          \
    for (int j = 0; j < 2; ++j)                                                \
      __builtin_amdgcn_global_load_lds(                                        \
          (AS1 void*)(Bs0 + (size_t)j * 64 * K + (ke)),                        \
          (AS3 void*)(lds + (sb) * 24576 + 16384 + j * 4096 + wdst), 16, 0, 0);\
  } while (0)
#define BARX() do {                                                            \
    __builtin_amdgcn_sched_barrier(0);                                         \
    __builtin_amdgcn_s_barrier();                                              \
    __builtin_amdgcn_sched_barrier(0);                                         \
  } while (0)
#define WAIT_VM6() do { __builtin_amdgcn_sched_barrier(0);                     \
    asm volatile("s_waitcnt vmcnt(6)" ::: "memory");                           \
    __builtin_amdgcn_sched_barrier(0); } while (0)
#define WAIT_VM0() do { __builtin_amdgcn_sched_barrier(0);                     \
    asm volatile("s_waitcnt vmcnt(0)" ::: "memory");                           \
    __builtin_amdgcn_sched_barrier(0); } while (0)
// PHASE: compute K-tile t (buf = t%3), optionally stage tile t+2.
// Plain-C++ ds_reads: compiler emits fine-grained lgkmcnt before dependent
// MFMAs (better than a hand lgkmcnt(0) drain).
#define PHASE(bufc, dostage, sb, ke, vmode) do {                               \
    if (dostage) STAGE(sb, ke);                                                \
    _Pragma("unroll")                                                          \
    for (int mi = 0; mi < 8; ++mi)                                             \
      af[mi] = *(const bfrag*)(lds + (bufc) * 24576 + roffA + mi * 1024);      \
    _Pragma("unroll")                                                          \
    for (int nj = 0; nj < 4; ++nj)                                             \
      bfr[nj] = *(const bfrag*)(lds + (bufc) * 24576 + 16384 + roffB + nj * 1024); \
    __builtin_amdgcn_s_setprio(1);                                             \
    _Pragma("unroll")                                                          \
    for (int mi = 0; mi < 8; ++mi)                                             \
      _Pragma("unroll")                                                        \
      for (int nj = 0; nj < 4; ++nj)                                           \
        acc[mi][nj] = __builtin_amdgcn_mfma_f32_16x16x32_bf16(                 \
            af[mi], bfr[nj], acc[mi][nj], 0, 0, 0);                            \
    __builtin_amdgcn_s_setprio(0);                                             \
    if (vmode == 1) WAIT_VM6();                                                \
    if (vmode == 2) WAIT_VM0();                                                \
    BARX();                                                                    \
  } while (0)

  // prologue: stage tiles 0,1 (12 loads); vmcnt(6) -> tile0 landed; barrier.
  STAGE(0, 0);
  STAGE(1, 32);
  asm volatile("s_waitcnt vmcnt(6)" ::: "memory");
  BARX();

  // 30 pipelined phases (stage t+2), then 2 drain phases.
#pragma unroll
  for (int tt = 0; tt < 30; tt += 3) {
    PHASE(0, true, 2, (tt + 2) * 32, 1);   // t = tt
    PHASE(1, true, 0, (tt + 3) * 32, 1);   // t = tt+1
    PHASE(2, true, 1, (tt + 4) * 32, 1);   // t = tt+2
  }
  PHASE(0, false, 0, 0, 2);                // t = 30: drain tile31's loads
  PHASE(1, false, 0, 0, 0);                // t = 31

  // ---- epilogue: act -> LDS C-tile (256 rows x 256 B, quad-XOR swizzled),
  // then 16 passes of ds_read_b128 -> coalesced 16B stores (256 B/row segs).
  {
#pragma unroll
    for (int nj = 0; nj < 4; ++nj) {
      const long n = n0 + wc * 64 + nj * 16 + fr;
      const float bv = bias[n];
      const bool is_tanh = (n < H_DIM);
      const int colb = (wc * 64 + nj * 16 + fr) * 2;
#pragma unroll
      for (int mi = 0; mi < 8; ++mi) {
        const int row0 = wr * 128 + mi * 16 + quad * 4;
#pragma unroll
        for (int reg = 0; reg < 4; ++reg) {
          const float y = acc[mi][nj][reg] + bv;
          const float a = is_tanh ? tanh_fast(y) : sigmoidf_(y);
          *(bf16_t*)(lds + ((((row0 + reg) * 256) + colb) ^ (quad << 5))) = (bf16_t)a;
        }
      }
    }
    __syncthreads();
#pragma unroll
    for (int p = 0; p < 16; ++p) {
      const int o = p * 4096 + tid * 16;
      const int rr = o >> 8;           // local row
      const int cb = o & 255;          // byte within row
      const float4 v = *(const float4*)(lds + (((rr * 256) + cb) ^ (((rr >> 2) & 3) << 5)));
      *(float4*)((char*)(Y + (size_t)(m0 + rr) * N + n0) + cb) = v;
    }
  }
#undef STAGE
#undef BARX
#undef WAIT_VM6
#undef WAIT_VM0
#undef PHASE
}

// ---------------- chunked parallel scan (bf16 Y, 2-wide vectorized) --------
__global__ __launch_bounds__(256) void scan_pass1(
    const bf16_t* __restrict__ Y, float* __restrict__ Ag, float* __restrict__ Dg)
{
  const int idx = blockIdx.x * 256 + threadIdx.x;   // g*8192 + b*512 + h2
  const int g = idx >> 13;
  const int b = (idx >> 9) & 15;
  const int h2 = idx & 511;
  const bf16_t* p = Y + ((size_t)(g * CHUNK * B_DIM + b)) * N3H + h2 * 2;
  float A0 = 1.0f, A1 = 1.0f, c0 = 0.0f, c1 = 0.0f;
  for (int i = 0; i < CHUNK; ++i) {
    const bf16x2 zv = *(const bf16x2*)(p);
    const bf16x2 fv = *(const bf16x2*)(p + H_DIM);
    const float f0 = (float)fv[0], f1 = (float)fv[1];
    const float a0 = 1.0f - f0,    a1 = 1.0f - f1;
    c0 = f0 * (float)zv[0] + a0 * c0;
    c1 = f1 * (float)zv[1] + a1 * c1;
    A0 *= a0;
    A1 *= a1;
    p += (size_t)B_DIM * N3H;
  }
  const int base = g * BH + b * H_DIM + h2 * 2;
  *(float2*)(Ag + base) = make_float2(A0, A1);
  *(float2*)(Dg + base) = make_float2(c0, c1);
}

__global__ __launch_bounds__(256) void scan_pass2(
    const float* __restrict__ Ag, const float* __restrict__ Dg,
    float* __restrict__ Cs)
{
  const int j = blockIdx.x * 256 + threadIdx.x;     // 0..16383
  float c = 0.0f;
#pragma unroll
  for (int g = 0; g < NCHUNK; ++g) {
    Cs[g * BH + j] = c;
    c = Dg[g * BH + j] + Ag[g * BH + j] * c;
  }
}

__global__ __launch_bounds__(256) void scan_pass3(
    const bf16_t* __restrict__ Y, const float* __restrict__ Cs,
    bf16_t* __restrict__ Xn, float* __restrict__ Out, const int last)
{
  const int idx = blockIdx.x * 256 + threadIdx.x;   // g*8192 + b*512 + h2
  const int g = idx >> 13;
  const int b = (idx >> 9) & 15;
  const int h2 = idx & 511;
  const bf16_t* p = Y + ((size_t)(g * CHUNK * B_DIM + b)) * N3H + h2 * 2;
  const int cb = g * BH + b * H_DIM + h2 * 2;
  float c0 = Cs[cb], c1 = Cs[cb + 1];
  size_t oo = (size_t)g * CHUNK * BH + (size_t)b * H_DIM + h2 * 2;
  for (int i = 0; i < CHUNK; ++i) {
    const bf16x2 zv = *(const bf16x2*)(p);
    const bf16x2 fv = *(const bf16x2*)(p + H_DIM);
    const bf16x2 ov = *(const bf16x2*)(p + 2 * H_DIM);
    const float f0 = (float)fv[0], f1 = (float)fv[1];
    c0 = f0 * (float)zv[0] + (1.0f - f0) * c0;
    c1 = f1 * (float)zv[1] + (1.0f - f1) * c1;
    const float v0 = (float)ov[0] * c0;
    const float v1 = (float)ov[1] * c1;
    if (last) {
      const int s = g * CHUNK + i;
      if (s < S_LEN - 1) *(float2*)(Out + oo) = make_float2(v0, v1);  // out = X[:-1]
    } else {
      bf16x2 w; w[0] = (__bf16)v0; w[1] = (__bf16)v1;
      *(bf16x2*)(Xn + oo) = w;
    }
    p += (size_t)B_DIM * N3H;
    oo += (size_t)BH;
  }
}

extern "C" void kernel_launch(void* const* d_in, const int* in_sizes, int n_in,
                              void* d_out, int out_size, void* d_ws, size_t ws_size,
                              hipStream_t stream)
{
  const int*   x   = (const int*)d_in[0];
  const float* emb = (const float*)d_in[1];
  const float* W[3]  = {(const float*)d_in[2], (const float*)d_in[4], (const float*)d_in[6]};
  const float* bv[3] = {(const float*)d_in[3], (const float*)d_in[5], (const float*)d_in[7]};
  float* out = (float*)d_out;

  char* ws = (char*)d_ws;
  bf16_t* Xbf = (bf16_t*)ws;                                // 67,108,864 B
  bf16_t* Wbf = (bf16_t*)(ws + 67108864);                   //  6,291,456 B
  bf16_t* Yb  = (bf16_t*)(ws + 67108864 + 6291456);         // 201,326,592 B
  char* tail  = ws + 67108864 + 6291456 + 201326592;
  float* Ag = (float*)tail;                                 // 2,097,152 B
  float* Dg = (float*)(tail + 2097152);                     // 2,097,152 B
  float* Cs = (float*)(tail + 4194304);                     // 2,097,152 B
  (void)ws_size;

  // 72 KiB dynamic LDS opt-in; host-side API, graph-capture safe.
  hipFuncSetAttribute((const void*)gemm_act_kernel,
                      hipFuncAttributeMaxDynamicSharedMemorySize, 73728);

  embed_kernel<<<M_DIM, 256, 0, stream>>>(x, emb, Xbf);

  for (int l = 0; l < 3; ++l) {
    const int last = (l == 2);
    cvtw_kernel<<<3072, 256, 0, stream>>>(W[l], Wbf);
    gemm_act_kernel<<<3072, 256, 73728, stream>>>(Xbf, Wbf, bv[l], Yb);
    scan_pass1<<<1024, 256, 0, stream>>>(Yb, Ag, Dg);
    scan_pass2<<<64, 256, 0, stream>>>(Ag, Dg, Cs);
    scan_pass3<<<1024, 256, 0, stream>>>(Yb, Cs, Xbf, out, last);
  }
}

// Round 4
// 1264.046 us; speedup vs baseline: 1.0481x; 1.0294x over previous
//
#include <hip/hip_runtime.h>
#include <hip/hip_bf16.h>

#define AS1 __attribute__((address_space(1)))
#define AS3 __attribute__((address_space(3)))

typedef __bf16 bf16_t;
typedef __attribute__((ext_vector_type(8))) __bf16 bfrag;
typedef __attribute__((ext_vector_type(4))) __bf16 bf16x4;
typedef __attribute__((ext_vector_type(2))) __bf16 bf16x2;
typedef __attribute__((ext_vector_type(4))) float ffrag;

#define S_LEN 2048
#define B_DIM 16
#define H_DIM 1024
#define N3H   3072
#define M_DIM 32768  /* S*B */
#define CHUNK 64
#define NCHUNK 32    /* S_LEN / CHUNK */
#define BH    16384  /* B*H */

__device__ __forceinline__ float sigmoidf_(float x) {
  return 1.0f / (1.0f + __expf(-x));
}
__device__ __forceinline__ float tanh_fast(float x) {
  return 2.0f / (1.0f + __expf(-2.0f * x)) - 1.0f;
}

// ---------------- embedding gather: X[s*B+b][h] = bf16(emb[x[s*B+b]][h]) ---
__global__ __launch_bounds__(256) void embed_kernel(
    const int* __restrict__ x, const float* __restrict__ emb,
    bf16_t* __restrict__ X)
{
  const int row = blockIdx.x;            // 0..32767 = s*16+b
  const int v = x[row];
  const float4* src = (const float4*)(emb + (size_t)v * H_DIM);
  float4 f = src[threadIdx.x];
  bf16x4 o;
  o.x = (__bf16)f.x; o.y = (__bf16)f.y; o.z = (__bf16)f.z; o.w = (__bf16)f.w;
  ((bf16x4*)X)[(size_t)row * (H_DIM / 4) + threadIdx.x] = o;
}

// ---------------- weight fp32 -> bf16 --------------------------------------
__global__ __launch_bounds__(256) void cvtw_kernel(
    const float* __restrict__ W, bf16_t* __restrict__ Wb)
{
  const size_t i = (size_t)blockIdx.x * 256 + threadIdx.x;  // float4 index
  float4 f = ((const float4*)W)[i];
  bf16x4 o;
  o.x = (__bf16)f.x; o.y = (__bf16)f.y; o.z = (__bf16)f.z; o.w = (__bf16)f.w;
  ((bf16x4*)Wb)[i] = o;
}

// ---------------- GEMM  Y = act(X * W^T + b) -------------------------------
// 256x128 tile, 4 waves (2M x 2N, wave-tile 128x64, acc[8][4]). K-tiles of 32,
// 3-buffer LDS rotation, stage 2 ahead, counted vmcnt(6), one barrier/phase.
// 72 KiB LDS -> 2 blocks/CU (m114 inter-block overlap).
//
// R4 change: XCD-LOCAL SUPERTILING. R3's n-fast order swept the 6 MB B panel
// through the 4 MB per-XCD L2 every 24 blocks -> staged loads were L2 misses
// to LLC (~500cy), outside the 2-phase prefetch window (FETCH 327 MB = 5x A's
// ideal). Each XCD owns 16m x 24n tiles; re-order into 4m x 8n supertiles:
// working set = 4x512KB (A) + 8x256KB (B) = 4 MB <= L2 -> staged loads hit L2
// (~200cy) inside the window. Everything else identical to R3.
__global__ __launch_bounds__(256, 2) void gemm_act_kernel(
    const bf16_t* __restrict__ A,
    const bf16_t* __restrict__ Bw,
    const float* __restrict__ bias,
    bf16_t* __restrict__ Y)
{
  constexpr int K = H_DIM;   // 1024 -> 32 K-tiles of 32
  constexpr int N = N3H;     // 3072
  extern __shared__ char lds[] __attribute__((aligned(16)));
  // buf b: A at b*24576 (16384 B = 256 rows x 32k), B at b*24576+16384 (8192 B)

  const int tid  = threadIdx.x;
  const int lane = tid & 63;
  const int wave = tid >> 6;     // 0..3
  const int wr = wave >> 1;      // 0..1  M half (128 rows)
  const int wc = wave & 1;       // 0..1  N half (64 cols)
  const int fr = lane & 15;
  const int quad = lane >> 4;

  // XCD swizzle + supertile: 3072 blocks = 8 XCDs x 384; per XCD 16m x 24n
  // tiles ordered as 4x3 supertiles of (4m x 8n) = 32 blocks each.
  const int bid = blockIdx.x;
  const int xcd = bid & 7;
  const int i   = bid >> 3;            // 0..383 within XCD
  const int st  = i >> 5;              // supertile 0..11
  const int j   = i & 31;              // 0..31 within supertile
  const int m_local = (st / 3) * 4 + (j >> 3);   // 0..15
  const int n_local = (st % 3) * 8 + (j & 7);    // 0..23
  const long m0 = (long)(xcd * 16 + m_local) * 256;
  const long n0 = (long)n_local * 128;

  // staging: thread -> (row = tid>>2 within 64-row group, pos = tid&3);
  // source chunk pre-swizzled by ((row>>1)&3) (== (tid>>3)&3).
  const int r  = tid >> 2;
  const int sc = ((tid & 3) ^ ((tid >> 3) & 3)) * 8;
  const bf16_t* As0 = A  + (m0 + r) * K + sc;
  const bf16_t* Bs0 = Bw + (n0 + r) * K + sc;
  const int wdst = wave * 1024;  // wave-uniform LDS dest offset per instr

  // fragment reads: A row = wr*128 + mi*16 + fr, B row = wc*64 + nj*16 + fr,
  // chunk pos = quad ^ ((fr>>1)&3)  (retrieves global k-octet = quad)
  const int cswz = (quad ^ ((fr >> 1) & 3)) * 16;
  const int roffA = wr * 8192 + fr * 64 + cswz;
  const int roffB = wc * 4096 + fr * 64 + cswz;

  ffrag acc[8][4] = {};
  bfrag af[8], bfr[4];

#define STAGE(sb, ke) do {                                                     \
    _Pragma("unroll")                                                          \
    for (int ii = 0; ii < 4; ++ii)                                             \
      __builtin_amdgcn_global_load_lds(                                        \
          (AS1 void*)(As0 + (size_t)ii * 64 * K + (ke)),                       \
          (AS3 void*)(lds + (sb) * 24576 + ii * 4096 + wdst), 16, 0, 0);       \
    _Pragma("unroll")                                                          \
    for (int jj = 0; jj < 2; ++jj)                                             \
      __builtin_amdgcn_global_load_lds(                                        \
          (AS1 void*)(Bs0 + (size_t)jj * 64 * K + (ke)),                       \
          (AS3 void*)(lds + (sb) * 24576 + 16384 + jj * 4096 + wdst), 16, 0, 0);\
  } while (0)
#define BARX() do {                                                            \
    __builtin_amdgcn_sched_barrier(0);                                         \
    __builtin_amdgcn_s_barrier();                                              \
    __builtin_amdgcn_sched_barrier(0);                                         \
  } while (0)
#define WAIT_VM6() do { __builtin_amdgcn_sched_barrier(0);                     \
    asm volatile("s_waitcnt vmcnt(6)" ::: "memory");                           \
    __builtin_amdgcn_sched_barrier(0); } while (0)
#define WAIT_VM0() do { __builtin_amdgcn_sched_barrier(0);                     \
    asm volatile("s_waitcnt vmcnt(0)" ::: "memory");                           \
    __builtin_amdgcn_sched_barrier(0); } while (0)
// PHASE: compute K-tile t (buf = t%3), optionally stage tile t+2.
// Plain-C++ ds_reads: compiler emits fine-grained lgkmcnt before dependent
// MFMAs (better than a hand lgkmcnt(0) drain).
#define PHASE(bufc, dostage, sb, ke, vmode) do {                               \
    if (dostage) STAGE(sb, ke);                                                \
    _Pragma("unroll")                                                          \
    for (int mi = 0; mi < 8; ++mi)                                             \
      af[mi] = *(const bfrag*)(lds + (bufc) * 24576 + roffA + mi * 1024);      \
    _Pragma("unroll")                                                          \
    for (int nj = 0; nj < 4; ++nj)                                             \
      bfr[nj] = *(const bfrag*)(lds + (bufc) * 24576 + 16384 + roffB + nj * 1024); \
    __builtin_amdgcn_s_setprio(1);                                             \
    _Pragma("unroll")                                                          \
    for (int mi = 0; mi < 8; ++mi)                                             \
      _Pragma("unroll")                                                        \
      for (int nj = 0; nj < 4; ++nj)                                           \
        acc[mi][nj] = __builtin_amdgcn_mfma_f32_16x16x32_bf16(                 \
            af[mi], bfr[nj], acc[mi][nj], 0, 0, 0);                            \
    __builtin_amdgcn_s_setprio(0);                                             \
    if (vmode == 1) WAIT_VM6();                                                \
    if (vmode == 2) WAIT_VM0();                                                \
    BARX();                                                                    \
  } while (0)

  // prologue: stage tiles 0,1 (12 loads); vmcnt(6) -> tile0 landed; barrier.
  STAGE(0, 0);
  STAGE(1, 32);
  asm volatile("s_waitcnt vmcnt(6)" ::: "memory");
  BARX();

  // 30 pipelined phases (stage t+2), then 2 drain phases.
#pragma unroll
  for (int tt = 0; tt < 30; tt += 3) {
    PHASE(0, true, 2, (tt + 2) * 32, 1);   // t = tt
    PHASE(1, true, 0, (tt + 3) * 32, 1);   // t = tt+1
    PHASE(2, true, 1, (tt + 4) * 32, 1);   // t = tt+2
  }
  PHASE(0, false, 0, 0, 2);                // t = 30: drain tile31's loads
  PHASE(1, false, 0, 0, 0);                // t = 31

  // ---- epilogue: act -> LDS C-tile (256 rows x 256 B, quad-XOR swizzled),
  // then 16 passes of ds_read_b128 -> coalesced 16B stores (256 B/row segs).
  {
#pragma unroll
    for (int nj = 0; nj < 4; ++nj) {
      const long n = n0 + wc * 64 + nj * 16 + fr;
      const float bv = bias[n];
      const bool is_tanh = (n < H_DIM);
      const int colb = (wc * 64 + nj * 16 + fr) * 2;
#pragma unroll
      for (int mi = 0; mi < 8; ++mi) {
        const int row0 = wr * 128 + mi * 16 + quad * 4;
#pragma unroll
        for (int reg = 0; reg < 4; ++reg) {
          const float y = acc[mi][nj][reg] + bv;
          const float a = is_tanh ? tanh_fast(y) : sigmoidf_(y);
          *(bf16_t*)(lds + ((((row0 + reg) * 256) + colb) ^ (quad << 5))) = (bf16_t)a;
        }
      }
    }
    __syncthreads();
#pragma unroll
    for (int p = 0; p < 16; ++p) {
      const int o = p * 4096 + tid * 16;
      const int rr = o >> 8;           // local row
      const int cb = o & 255;          // byte within row
      const float4 v = *(const float4*)(lds + (((rr * 256) + cb) ^ (((rr >> 2) & 3) << 5)));
      *(float4*)((char*)(Y + (size_t)(m0 + rr) * N + n0) + cb) = v;
    }
  }
#undef STAGE
#undef BARX
#undef WAIT_VM6
#undef WAIT_VM0
#undef PHASE
}

// ---------------- chunked parallel scan (bf16 Y, 2-wide vectorized) --------
__global__ __launch_bounds__(256) void scan_pass1(
    const bf16_t* __restrict__ Y, float* __restrict__ Ag, float* __restrict__ Dg)
{
  const int idx = blockIdx.x * 256 + threadIdx.x;   // g*8192 + b*512 + h2
  const int g = idx >> 13;
  const int b = (idx >> 9) & 15;
  const int h2 = idx & 511;
  const bf16_t* p = Y + ((size_t)(g * CHUNK * B_DIM + b)) * N3H + h2 * 2;
  float A0 = 1.0f, A1 = 1.0f, c0 = 0.0f, c1 = 0.0f;
  for (int i = 0; i < CHUNK; ++i) {
    const bf16x2 zv = *(const bf16x2*)(p);
    const bf16x2 fv = *(const bf16x2*)(p + H_DIM);
    const float f0 = (float)fv[0], f1 = (float)fv[1];
    const float a0 = 1.0f - f0,    a1 = 1.0f - f1;
    c0 = f0 * (float)zv[0] + a0 * c0;
    c1 = f1 * (float)zv[1] + a1 * c1;
    A0 *= a0;
    A1 *= a1;
    p += (size_t)B_DIM * N3H;
  }
  const int base = g * BH + b * H_DIM + h2 * 2;
  *(float2*)(Ag + base) = make_float2(A0, A1);
  *(float2*)(Dg + base) = make_float2(c0, c1);
}

__global__ __launch_bounds__(256) void scan_pass2(
    const float* __restrict__ Ag, const float* __restrict__ Dg,
    float* __restrict__ Cs)
{
  const int j = blockIdx.x * 256 + threadIdx.x;     // 0..16383
  float c = 0.0f;
#pragma unroll
  for (int g = 0; g < NCHUNK; ++g) {
    Cs[g * BH + j] = c;
    c = Dg[g * BH + j] + Ag[g * BH + j] * c;
  }
}

__global__ __launch_bounds__(256) void scan_pass3(
    const bf16_t* __restrict__ Y, const float* __restrict__ Cs,
    bf16_t* __restrict__ Xn, float* __restrict__ Out, const int last)
{
  const int idx = blockIdx.x * 256 + threadIdx.x;   // g*8192 + b*512 + h2
  const int g = idx >> 13;
  const int b = (idx >> 9) & 15;
  const int h2 = idx & 511;
  const bf16_t* p = Y + ((size_t)(g * CHUNK * B_DIM + b)) * N3H + h2 * 2;
  const int cb = g * BH + b * H_DIM + h2 * 2;
  float c0 = Cs[cb], c1 = Cs[cb + 1];
  size_t oo = (size_t)g * CHUNK * BH + (size_t)b * H_DIM + h2 * 2;
  for (int i = 0; i < CHUNK; ++i) {
    const bf16x2 zv = *(const bf16x2*)(p);
    const bf16x2 fv = *(const bf16x2*)(p + H_DIM);
    const bf16x2 ov = *(const bf16x2*)(p + 2 * H_DIM);
    const float f0 = (float)fv[0], f1 = (float)fv[1];
    c0 = f0 * (float)zv[0] + (1.0f - f0) * c0;
    c1 = f1 * (float)zv[1] + (1.0f - f1) * c1;
    const float v0 = (float)ov[0] * c0;
    const float v1 = (float)ov[1] * c1;
    if (last) {
      const int s = g * CHUNK + i;
      if (s < S_LEN - 1) *(float2*)(Out + oo) = make_float2(v0, v1);  // out = X[:-1]
    } else {
      bf16x2 w; w[0] = (__bf16)v0; w[1] = (__bf16)v1;
      *(bf16x2*)(Xn + oo) = w;
    }
    p += (size_t)B_DIM * N3H;
    oo += (size_t)BH;
  }
}

extern "C" void kernel_launch(void* const* d_in, const int* in_sizes, int n_in,
                              void* d_out, int out_size, void* d_ws, size_t ws_size,
                              hipStream_t stream)
{
  const int*   x   = (const int*)d_in[0];
  const float* emb = (const float*)d_in[1];
  const float* W[3]  = {(const float*)d_in[2], (const float*)d_in[4], (const float*)d_in[6]};
  const float* bv[3] = {(const float*)d_in[3], (const float*)d_in[5], (const float*)d_in[7]};
  float* out = (float*)d_out;

  char* ws = (char*)d_ws;
  bf16_t* Xbf = (bf16_t*)ws;                                // 67,108,864 B
  bf16_t* Wbf = (bf16_t*)(ws + 67108864);                   //  6,291,456 B
  bf16_t* Yb  = (bf16_t*)(ws + 67108864 + 6291456);         // 201,326,592 B
  char* tail  = ws + 67108864 + 6291456 + 201326592;
  float* Ag = (float*)tail;                                 // 2,097,152 B
  float* Dg = (float*)(tail + 2097152);                     // 2,097,152 B
  float* Cs = (float*)(tail + 4194304);                     // 2,097,152 B
  (void)ws_size;

  // 72 KiB dynamic LDS opt-in; host-side API, graph-capture safe.
  hipFuncSetAttribute((const void*)gemm_act_kernel,
                      hipFuncAttributeMaxDynamicSharedMemorySize, 73728);

  embed_kernel<<<M_DIM, 256, 0, stream>>>(x, emb, Xbf);

  for (int l = 0; l < 3; ++l) {
    const int last = (l == 2);
    cvtw_kernel<<<3072, 256, 0, stream>>>(W[l], Wbf);
    gemm_act_kernel<<<3072, 256, 73728, stream>>>(Xbf, Wbf, bv[l], Yb);
    scan_pass1<<<1024, 256, 0, stream>>>(Yb, Ag, Dg);
    scan_pass2<<<64, 256, 0, stream>>>(Ag, Dg, Cs);
    scan_pass3<<<1024, 256, 0, stream>>>(Yb, Cs, Xbf, out, last);
  }
}

// Round 5
// 1195.874 us; speedup vs baseline: 1.1079x; 1.0570x over previous
//
#include <hip/hip_runtime.h>
#include <hip/hip_bf16.h>

#define AS1 __attribute__((address_space(1)))
#define AS3 __attribute__((address_space(3)))

typedef __bf16 bf16_t;
typedef __attribute__((ext_vector_type(8))) __bf16 bfrag;
typedef __attribute__((ext_vector_type(4))) __bf16 bf16x4;
typedef __attribute__((ext_vector_type(2))) __bf16 bf16x2;
typedef __attribute__((ext_vector_type(4))) float ffrag;

#define S_LEN 2048
#define B_DIM 16
#define H_DIM 1024
#define N3H   3072
#define M_DIM 32768  /* S*B */
#define CHUNK 64
#define NCHUNK 32    /* S_LEN / CHUNK */
#define BH    16384  /* B*H */

__device__ __forceinline__ float sigmoidf_(float x) {
  return 1.0f / (1.0f + __expf(-x));
}
__device__ __forceinline__ float tanh_fast(float x) {
  return 2.0f / (1.0f + __expf(-2.0f * x)) - 1.0f;
}

// ---------------- embedding gather: X[s*B+b][h] = bf16(emb[x[s*B+b]][h]) ---
__global__ __launch_bounds__(256) void embed_kernel(
    const int* __restrict__ x, const float* __restrict__ emb,
    bf16_t* __restrict__ X)
{
  const int row = blockIdx.x;            // 0..32767 = s*16+b
  const int v = x[row];
  const float4* src = (const float4*)(emb + (size_t)v * H_DIM);
  float4 f = src[threadIdx.x];
  bf16x4 o;
  o.x = (__bf16)f.x; o.y = (__bf16)f.y; o.z = (__bf16)f.z; o.w = (__bf16)f.w;
  ((bf16x4*)X)[(size_t)row * (H_DIM / 4) + threadIdx.x] = o;
}

// ---------------- weight fp32 -> bf16 --------------------------------------
__global__ __launch_bounds__(256) void cvtw_kernel(
    const float* __restrict__ W, bf16_t* __restrict__ Wb)
{
  const size_t i = (size_t)blockIdx.x * 256 + threadIdx.x;  // float4 index
  float4 f = ((const float4*)W)[i];
  bf16x4 o;
  o.x = (__bf16)f.x; o.y = (__bf16)f.y; o.z = (__bf16)f.z; o.w = (__bf16)f.w;
  ((bf16x4*)Wb)[i] = o;
}

// ---------------- GEMM  Y = act(X * W^T + b) -------------------------------
// 256x128 tile, 4 waves (2M x 2N, wave-tile 128x64, acc[8][4]). K-tiles of 32,
// 3-buffer LDS rotation, stage 2 ahead, counted vmcnt(6), one barrier/phase.
// 72 KiB LDS -> 2 blocks/CU (m114 inter-block overlap). XCD-local supertiling
// (R4): per-XCD 4m x 8n supertiles keep the staged working set at 4 MB <= L2
// (FETCH 327->183 MB, verified).
//
// R5 change: PHASE ORDER reads-first. R3/R4 issued the 6 global_load_lds
// (LDS-writing VMEM) immediately BEFORE the phase's ds_reads; the compiler
// must order possibly-aliasing LDS ops and inserts a conservative vmcnt wait
// before the first ds_read -> every phase serialized behind the just-issued
// staging loads' L2 latency (~1900 idle cy/slot; MfmaUtil stuck at 37%).
// Proven-fast template order (R1 kernel / m201): ds_reads FIRST, then stage,
// then MFMA, then counted vmcnt, then barrier. sched_barrier(0) pins
// reads-before-stage so the scheduler cannot recreate the bad order.
__global__ __launch_bounds__(256, 2) void gemm_act_kernel(
    const bf16_t* __restrict__ A,
    const bf16_t* __restrict__ Bw,
    const float* __restrict__ bias,
    bf16_t* __restrict__ Y)
{
  constexpr int K = H_DIM;   // 1024 -> 32 K-tiles of 32
  constexpr int N = N3H;     // 3072
  extern __shared__ char lds[] __attribute__((aligned(16)));
  // buf b: A at b*24576 (16384 B = 256 rows x 32k), B at b*24576+16384 (8192 B)

  const int tid  = threadIdx.x;
  const int lane = tid & 63;
  const int wave = tid >> 6;     // 0..3
  const int wr = wave >> 1;      // 0..1  M half (128 rows)
  const int wc = wave & 1;       // 0..1  N half (64 cols)
  const int fr = lane & 15;
  const int quad = lane >> 4;

  // XCD swizzle + supertile: 3072 blocks = 8 XCDs x 384; per XCD 16m x 24n
  // tiles ordered as 4x3 supertiles of (4m x 8n) = 32 blocks each.
  const int bid = blockIdx.x;
  const int xcd = bid & 7;
  const int i   = bid >> 3;            // 0..383 within XCD
  const int st  = i >> 5;              // supertile 0..11
  const int j   = i & 31;              // 0..31 within supertile
  const int m_local = (st / 3) * 4 + (j >> 3);   // 0..15
  const int n_local = (st % 3) * 8 + (j & 7);    // 0..23
  const long m0 = (long)(xcd * 16 + m_local) * 256;
  const long n0 = (long)n_local * 128;

  // staging: thread -> (row = tid>>2 within 64-row group, pos = tid&3);
  // source chunk pre-swizzled by ((row>>1)&3) (== (tid>>3)&3).
  const int r  = tid >> 2;
  const int sc = ((tid & 3) ^ ((tid >> 3) & 3)) * 8;
  const bf16_t* As0 = A  + (m0 + r) * K + sc;
  const bf16_t* Bs0 = Bw + (n0 + r) * K + sc;
  const int wdst = wave * 1024;  // wave-uniform LDS dest offset per instr

  // fragment reads: A row = wr*128 + mi*16 + fr, B row = wc*64 + nj*16 + fr,
  // chunk pos = quad ^ ((fr>>1)&3)  (retrieves global k-octet = quad)
  const int cswz = (quad ^ ((fr >> 1) & 3)) * 16;
  const int roffA = wr * 8192 + fr * 64 + cswz;
  const int roffB = wc * 4096 + fr * 64 + cswz;

  ffrag acc[8][4] = {};
  bfrag af[8], bfr[4];

#define STAGE(sb, ke) do {                                                     \
    _Pragma("unroll")                                                          \
    for (int ii = 0; ii < 4; ++ii)                                             \
      __builtin_amdgcn_global_load_lds(                                        \
          (AS1 void*)(As0 + (size_t)ii * 64 * K + (ke)),                       \
          (AS3 void*)(lds + (sb) * 24576 + ii * 4096 + wdst), 16, 0, 0);       \
    _Pragma("unroll")                                                          \
    for (int jj = 0; jj < 2; ++jj)                                             \
      __builtin_amdgcn_global_load_lds(                                        \
          (AS1 void*)(Bs0 + (size_t)jj * 64 * K + (ke)),                       \
          (AS3 void*)(lds + (sb) * 24576 + 16384 + jj * 4096 + wdst), 16, 0, 0);\
  } while (0)
#define BARX() do {                                                            \
    __builtin_amdgcn_sched_barrier(0);                                         \
    __builtin_amdgcn_s_barrier();                                              \
    __builtin_amdgcn_sched_barrier(0);                                         \
  } while (0)
#define WAIT_VM6() do { __builtin_amdgcn_sched_barrier(0);                     \
    asm volatile("s_waitcnt vmcnt(6)" ::: "memory");                           \
    __builtin_amdgcn_sched_barrier(0); } while (0)
#define WAIT_VM0() do { __builtin_amdgcn_sched_barrier(0);                     \
    asm volatile("s_waitcnt vmcnt(0)" ::: "memory");                           \
    __builtin_amdgcn_sched_barrier(0); } while (0)
// PHASE: compute K-tile t (buf = t%3), optionally stage tile t+2.
// Order (R5): ds_reads FIRST -> pin -> stage -> MFMA -> counted vmcnt -> bar.
// Plain-C++ ds_reads: compiler emits fine-grained lgkmcnt before dependent
// MFMAs, so MFMAs start on first-fragment arrival.
#define PHASE(bufc, dostage, sb, ke, vmode) do {                               \
    _Pragma("unroll")                                                          \
    for (int mi = 0; mi < 8; ++mi)                                             \
      af[mi] = *(const bfrag*)(lds + (bufc) * 24576 + roffA + mi * 1024);      \
    _Pragma("unroll")                                                          \
    for (int nj = 0; nj < 4; ++nj)                                             \
      bfr[nj] = *(const bfrag*)(lds + (bufc) * 24576 + 16384 + roffB + nj * 1024); \
    __builtin_amdgcn_sched_barrier(0);  /* reads stay ahead of staging */      \
    if (dostage) STAGE(sb, ke);                                                \
    __builtin_amdgcn_s_setprio(1);                                             \
    _Pragma("unroll")                                                          \
    for (int mi = 0; mi < 8; ++mi)                                             \
      _Pragma("unroll")                                                        \
      for (int nj = 0; nj < 4; ++nj)                                           \
        acc[mi][nj] = __builtin_amdgcn_mfma_f32_16x16x32_bf16(                 \
            af[mi], bfr[nj], acc[mi][nj], 0, 0, 0);                            \
    __builtin_amdgcn_s_setprio(0);                                             \
    if (vmode == 1) WAIT_VM6();                                                \
    if (vmode == 2) WAIT_VM0();                                                \
    BARX();                                                                    \
  } while (0)

  // prologue: stage tiles 0,1 (12 loads); vmcnt(6) -> tile0 landed; barrier.
  STAGE(0, 0);
  STAGE(1, 32);
  asm volatile("s_waitcnt vmcnt(6)" ::: "memory");
  BARX();

  // 30 pipelined phases (stage t+2), then 2 drain phases.
#pragma unroll
  for (int tt = 0; tt < 30; tt += 3) {
    PHASE(0, true, 2, (tt + 2) * 32, 1);   // t = tt
    PHASE(1, true, 0, (tt + 3) * 32, 1);   // t = tt+1
    PHASE(2, true, 1, (tt + 4) * 32, 1);   // t = tt+2
  }
  PHASE(0, false, 0, 0, 2);                // t = 30: drain tile31's loads
  PHASE(1, false, 0, 0, 0);                // t = 31

  // ---- epilogue: act -> LDS C-tile (256 rows x 256 B, quad-XOR swizzled),
  // then 16 passes of ds_read_b128 -> coalesced 16B stores (256 B/row segs).
  {
#pragma unroll
    for (int nj = 0; nj < 4; ++nj) {
      const long n = n0 + wc * 64 + nj * 16 + fr;
      const float bv = bias[n];
      const bool is_tanh = (n < H_DIM);
      const int colb = (wc * 64 + nj * 16 + fr) * 2;
#pragma unroll
      for (int mi = 0; mi < 8; ++mi) {
        const int row0 = wr * 128 + mi * 16 + quad * 4;
#pragma unroll
        for (int reg = 0; reg < 4; ++reg) {
          const float y = acc[mi][nj][reg] + bv;
          const float a = is_tanh ? tanh_fast(y) : sigmoidf_(y);
          *(bf16_t*)(lds + ((((row0 + reg) * 256) + colb) ^ (quad << 5))) = (bf16_t)a;
        }
      }
    }
    __syncthreads();
#pragma unroll
    for (int p = 0; p < 16; ++p) {
      const int o = p * 4096 + tid * 16;
      const int rr = o >> 8;           // local row
      const int cb = o & 255;          // byte within row
      const float4 v = *(const float4*)(lds + (((rr * 256) + cb) ^ (((rr >> 2) & 3) << 5)));
      *(float4*)((char*)(Y + (size_t)(m0 + rr) * N + n0) + cb) = v;
    }
  }
#undef STAGE
#undef BARX
#undef WAIT_VM6
#undef WAIT_VM0
#undef PHASE
}

// ---------------- chunked parallel scan (bf16 Y, 2-wide vectorized) --------
__global__ __launch_bounds__(256) void scan_pass1(
    const bf16_t* __restrict__ Y, float* __restrict__ Ag, float* __restrict__ Dg)
{
  const int idx = blockIdx.x * 256 + threadIdx.x;   // g*8192 + b*512 + h2
  const int g = idx >> 13;
  const int b = (idx >> 9) & 15;
  const int h2 = idx & 511;
  const bf16_t* p = Y + ((size_t)(g * CHUNK * B_DIM + b)) * N3H + h2 * 2;
  float A0 = 1.0f, A1 = 1.0f, c0 = 0.0f, c1 = 0.0f;
  for (int i = 0; i < CHUNK; ++i) {
    const bf16x2 zv = *(const bf16x2*)(p);
    const bf16x2 fv = *(const bf16x2*)(p + H_DIM);
    const float f0 = (float)fv[0], f1 = (float)fv[1];
    const float a0 = 1.0f - f0,    a1 = 1.0f - f1;
    c0 = f0 * (float)zv[0] + a0 * c0;
    c1 = f1 * (float)zv[1] + a1 * c1;
    A0 *= a0;
    A1 *= a1;
    p += (size_t)B_DIM * N3H;
  }
  const int base = g * BH + b * H_DIM + h2 * 2;
  *(float2*)(Ag + base) = make_float2(A0, A1);
  *(float2*)(Dg + base) = make_float2(c0, c1);
}

__global__ __launch_bounds__(256) void scan_pass2(
    const float* __restrict__ Ag, const float* __restrict__ Dg,
    float* __restrict__ Cs)
{
  const int j = blockIdx.x * 256 + threadIdx.x;     // 0..16383
  float c = 0.0f;
#pragma unroll
  for (int g = 0; g < NCHUNK; ++g) {
    Cs[g * BH + j] = c;
    c = Dg[g * BH + j] + Ag[g * BH + j] * c;
  }
}

__global__ __launch_bounds__(256) void scan_pass3(
    const bf16_t* __restrict__ Y, const float* __restrict__ Cs,
    bf16_t* __restrict__ Xn, float* __restrict__ Out, const int last)
{
  const int idx = blockIdx.x * 256 + threadIdx.x;   // g*8192 + b*512 + h2
  const int g = idx >> 13;
  const int b = (idx >> 9) & 15;
  const int h2 = idx & 511;
  const bf16_t* p = Y + ((size_t)(g * CHUNK * B_DIM + b)) * N3H + h2 * 2;
  const int cb = g * BH + b * H_DIM + h2 * 2;
  float c0 = Cs[cb], c1 = Cs[cb + 1];
  size_t oo = (size_t)g * CHUNK * BH + (size_t)b * H_DIM + h2 * 2;
  for (int i = 0; i < CHUNK; ++i) {
    const bf16x2 zv = *(const bf16x2*)(p);
    const bf16x2 fv = *(const bf16x2*)(p + H_DIM);
    const bf16x2 ov = *(const bf16x2*)(p + 2 * H_DIM);
    const float f0 = (float)fv[0], f1 = (float)fv[1];
    c0 = f0 * (float)zv[0] + (1.0f - f0) * c0;
    c1 = f1 * (float)zv[1] + (1.0f - f1) * c1;
    const float v0 = (float)ov[0] * c0;
    const float v1 = (float)ov[1] * c1;
    if (last) {
      const int s = g * CHUNK + i;
      if (s < S_LEN - 1) *(float2*)(Out + oo) = make_float2(v0, v1);  // out = X[:-1]
    } else {
      bf16x2 w; w[0] = (__bf16)v0; w[1] = (__bf16)v1;
      *(bf16x2*)(Xn + oo) = w;
    }
    p += (size_t)B_DIM * N3H;
    oo += (size_t)BH;
  }
}

extern "C" void kernel_launch(void* const* d_in, const int* in_sizes, int n_in,
                              void* d_out, int out_size, void* d_ws, size_t ws_size,
                              hipStream_t stream)
{
  const int*   x   = (const int*)d_in[0];
  const float* emb = (const float*)d_in[1];
  const float* W[3]  = {(const float*)d_in[2], (const float*)d_in[4], (const float*)d_in[6]};
  const float* bv[3] = {(const float*)d_in[3], (const float*)d_in[5], (const float*)d_in[7]};
  float* out = (float*)d_out;

  char* ws = (char*)d_ws;
  bf16_t* Xbf = (bf16_t*)ws;                                // 67,108,864 B
  bf16_t* Wbf = (bf16_t*)(ws + 67108864);                   //  6,291,456 B
  bf16_t* Yb  = (bf16_t*)(ws + 67108864 + 6291456);         // 201,326,592 B
  char* tail  = ws + 67108864 + 6291456 + 201326592;
  float* Ag = (float*)tail;                                 // 2,097,152 B
  float* Dg = (float*)(tail + 2097152);                     // 2,097,152 B
  float* Cs = (float*)(tail + 4194304);                     // 2,097,152 B
  (void)ws_size;

  // 72 KiB dynamic LDS opt-in; host-side API, graph-capture safe.
  hipFuncSetAttribute((const void*)gemm_act_kernel,
                      hipFuncAttributeMaxDynamicSharedMemorySize, 73728);

  embed_kernel<<<M_DIM, 256, 0, stream>>>(x, emb, Xbf);

  for (int l = 0; l < 3; ++l) {
    const int last = (l == 2);
    cvtw_kernel<<<3072, 256, 0, stream>>>(W[l], Wbf);
    gemm_act_kernel<<<3072, 256, 73728, stream>>>(Xbf, Wbf, bv[l], Yb);
    scan_pass1<<<1024, 256, 0, stream>>>(Yb, Ag, Dg);
    scan_pass2<<<64, 256, 0, stream>>>(Ag, Dg, Cs);
    scan_pass3<<<1024, 256, 0, stream>>>(Yb, Cs, Xbf, out, last);
  }
}